// Round 4
// baseline (868.448 us; speedup 1.0000x reference)
//
#include <hip/hip_runtime.h>

// ---------- types ----------
typedef short bf16x8 __attribute__((ext_vector_type(8)));
typedef short bf16x4 __attribute__((ext_vector_type(4)));
typedef float f32x4  __attribute__((ext_vector_type(4)));

// ---------- bf16 helpers (bit-level, RNE) ----------
__device__ inline unsigned short f2bf(float f){
  unsigned u = __float_as_uint(f);
  u += 0x7fffu + ((u >> 16) & 1u);
  return (unsigned short)(u >> 16);
}
__device__ inline float bf2f(unsigned short s){
  return __uint_as_float(((unsigned)s) << 16);
}
// x ~= h + m + l (~24 mantissa bits)
__device__ inline void split3v(float x, short& h, short& m, short& l){
  unsigned short hh = f2bf(x); float r1 = x - bf2f(hh);
  unsigned short mm = f2bf(r1); float r2 = r1 - bf2f(mm);
  h = (short)hh; m = (short)mm; l = (short)f2bf(r2);
}
__device__ inline void split2v(float x, short& h, short& m){
  unsigned short hh = f2bf(x); float r1 = x - bf2f(hh);
  h = (short)hh; m = (short)f2bf(r1);
}

// ---------- kernel 1: spectral projection + patchify + split3 ----------
// hs (4,128,512,512) fp32, sm (128,3) -> hp_{h,m,l} (4,1024,768) bf16 row-major
// block: 4 patches; thread t -> (n_local = t>>6, py = (t>>2)&15, pxq = (t&3)*4)
__global__ __launch_bounds__(256) void k_spectral(const float* __restrict__ hs,
                                                  const float* __restrict__ sm,
                                                  short* __restrict__ hph,
                                                  short* __restrict__ hpm,
                                                  short* __restrict__ hpl){
  __shared__ float ssm[384];
  int t = threadIdx.x;
  if (t < 128){ ssm[t] = sm[t]; ssm[t+128] = sm[t+128]; ssm[t+256] = sm[t+256]; }
  __syncthreads();
  int b = blockIdx.y;
  int n = blockIdx.x * 4 + (t >> 6);       // patch 0..1023
  int py  = (t >> 2) & 15;
  int pxq = (t & 3) * 4;
  int y = ((n >> 5) << 4) + py;
  int x = ((n & 31) << 4) + pxq;
  const float* p = hs + (size_t)b * 128 * 262144 + (size_t)y * 512 + x;
  float acc[3][4] = {};
  #pragma unroll 4
  for (int c = 0; c < 128; c++){
    float4 v = *(const float4*)(p + (size_t)c * 262144);
    float w0 = ssm[c*3+0], w1 = ssm[c*3+1], w2 = ssm[c*3+2];
    acc[0][0] = fmaf(v.x, w0, acc[0][0]); acc[0][1] = fmaf(v.y, w0, acc[0][1]);
    acc[0][2] = fmaf(v.z, w0, acc[0][2]); acc[0][3] = fmaf(v.w, w0, acc[0][3]);
    acc[1][0] = fmaf(v.x, w1, acc[1][0]); acc[1][1] = fmaf(v.y, w1, acc[1][1]);
    acc[1][2] = fmaf(v.z, w1, acc[1][2]); acc[1][3] = fmaf(v.w, w1, acc[1][3]);
    acc[2][0] = fmaf(v.x, w2, acc[2][0]); acc[2][1] = fmaf(v.y, w2, acc[2][1]);
    acc[2][2] = fmaf(v.z, w2, acc[2][2]); acc[2][3] = fmaf(v.w, w2, acc[2][3]);
  }
  size_t base = ((size_t)((b << 10) + n)) * 768 + py*16 + pxq;
  #pragma unroll
  for (int c = 0; c < 3; c++){
    short h[4], m[4], l[4];
    #pragma unroll
    for (int e = 0; e < 4; e++) split3v(acc[c][e], h[e], m[e], l[e]);
    *(bf16x4*)(hph + base + c*256) = (bf16x4){h[0],h[1],h[2],h[3]};
    *(bf16x4*)(hpm + base + c*256) = (bf16x4){m[0],m[1],m[2],m[3]};
    *(bf16x4*)(hpl + base + c*256) = (bf16x4){l[0],l[1],l[2],l[3]};
  }
}

// ---------- kernel 2: ms depthwise conv + patchify + split3 ----------
// block = one patch; stage 18x18x3 window in LDS; thread (py,px)
__global__ __launch_bounds__(256) void k_msprep(const float* __restrict__ ms,
                                                const float* __restrict__ kw,
                                                short* __restrict__ mph,
                                                short* __restrict__ mpm,
                                                short* __restrict__ mpl){
  int b = blockIdx.y, n = blockIdx.x;
  int Y0 = ((n >> 5) << 4) - 1, X0 = ((n & 31) << 4) - 1;
  __shared__ float win[3][18][18];
  int t = threadIdx.x;
  for (int i = t; i < 972; i += 256){
    int c = i / 324, r = i % 324;
    int yy = Y0 + r / 18, xx = X0 + r % 18;
    win[c][r/18][r%18] = (yy >= 0 && yy < 512 && xx >= 0 && xx < 512)
        ? ms[(size_t)(b*3 + c) * 262144 + (size_t)yy * 512 + xx] : 0.f;
  }
  __syncthreads();
  int py = t >> 4, px = t & 15;
  size_t base = ((size_t)((b << 10) + n)) * 768 + py*16 + px;
  #pragma unroll
  for (int c = 0; c < 3; c++){
    float conv = 0.f;
    #pragma unroll
    for (int dy = 0; dy < 3; dy++)
      #pragma unroll
      for (int dx = 0; dx < 3; dx++)
        conv = fmaf(win[c][py+dy][px+dx], kw[c*9 + dy*3 + dx], conv);
    short h, m, l; split3v(conv, h, m, l);
    mph[base + c*256] = h; mpm[base + c*256] = m; mpl[base + c*256] = l;
  }
}

// ---------- kernel 3: bf16 transpose (b,1024,768) -> (b,768,1024) ----------
__global__ __launch_bounds__(256) void k_transpose(const short* __restrict__ src,
                                                   short* __restrict__ dst){
  __shared__ short tile[64][65];
  int n0 = blockIdx.x * 64, d0 = blockIdx.y * 64, b = blockIdx.z;
  const short* s = src + (size_t)b * 786432;
  short* d = dst + (size_t)b * 786432;
  int tx = threadIdx.x & 63, ty = threadIdx.x >> 6;
  #pragma unroll
  for (int i = 0; i < 16; i++){
    int r = i*4 + ty;
    tile[r][tx] = s[(size_t)(n0 + r) * 768 + d0 + tx];
  }
  __syncthreads();
  #pragma unroll
  for (int i = 0; i < 16; i++){
    int r = i*4 + ty;
    d[(size_t)(d0 + r) * 1024 + n0 + tx] = tile[tx][r];
  }
}

// ---------- kernel 4/6: GEMM on pre-split bf16 components ----------
// C[row,col] = sum_k A[row,k]*B[col,k]; A rows 1024 (stride SA shorts),
// B rows NC (stride SB shorts). NSPLIT=3 -> 6 products; NSPLIT=2 -> 3.
// MODE 0: C = sim fp32 (ldc=1024). MODE 1: out ch 0..2 unresize layout.
template<int MODE, int K, int SA, int SB, int NSPLIT>
__global__ __launch_bounds__(256) void k_gemm(const short* __restrict__ Ah,
                                              const short* __restrict__ Am,
                                              const short* __restrict__ Al,
                                              const short* __restrict__ Bh,
                                              const short* __restrict__ Bm,
                                              const short* __restrict__ Bl,
                                              float* __restrict__ C,
                                              float* __restrict__ out){
  __shared__ short lds[2*NSPLIT][128][40];

  const int t  = threadIdx.x;
  const int b  = blockIdx.z;
  const int n0 = blockIdx.x * 128;   // col block
  const int m0 = blockIdx.y * 128;   // row block
  const size_t aoff = (size_t)b * 1024 * SA;
  const size_t boff = (size_t)b * (MODE == 0 ? 1024 : 768) * SB;

  const int lane = t & 63;
  const int wid  = t >> 6;
  const int wr = (wid >> 1) * 64;
  const int wc = (wid & 1) * 64;
  const int lrow = lane & 15;
  const int lg   = lane >> 4;

  f32x4 acc[4][4];
  #pragma unroll
  for (int i = 0; i < 4; i++)
    #pragma unroll
    for (int j = 0; j < 4; j++)
      acc[i][j] = (f32x4){0.f, 0.f, 0.f, 0.f};

  for (int k0 = 0; k0 < K; k0 += 32){
    // stage: each thread copies 16B chunks; 512 chunk-slots per comp pair
    #pragma unroll
    for (int p = 0; p < 2; p++){
      int idx = t + p*256;           // 0..511
      int row = idx >> 2;            // 0..127
      int kc  = (idx & 3) * 8;       // 0,8,16,24
      size_t sa = aoff + (size_t)(m0 + row) * SA + k0 + kc;
      size_t sb = boff + (size_t)(n0 + row) * SB + k0 + kc;
      *(bf16x8*)&lds[0][row][kc] = *(const bf16x8*)(Ah + sa);
      *(bf16x8*)&lds[1][row][kc] = *(const bf16x8*)(Am + sa);
      if (NSPLIT == 3) *(bf16x8*)&lds[2][row][kc] = *(const bf16x8*)(Al + sa);
      *(bf16x8*)&lds[NSPLIT+0][row][kc] = *(const bf16x8*)(Bh + sb);
      *(bf16x8*)&lds[NSPLIT+1][row][kc] = *(const bf16x8*)(Bm + sb);
      if (NSPLIT == 3) *(bf16x8*)&lds[NSPLIT+2][row][kc] = *(const bf16x8*)(Bl + sb);
    }
    __syncthreads();

    bf16x8 afh[4], afm[4], afl[4];
    #pragma unroll
    for (int i = 0; i < 4; i++){
      int r = wr + i*16 + lrow;
      afh[i] = *(const bf16x8*)&lds[0][r][lg*8];
      afm[i] = *(const bf16x8*)&lds[1][r][lg*8];
      if (NSPLIT == 3) afl[i] = *(const bf16x8*)&lds[2][r][lg*8];
    }
    #pragma unroll
    for (int j = 0; j < 4; j++){
      int r = wc + j*16 + lrow;
      bf16x8 bh = *(const bf16x8*)&lds[NSPLIT+0][r][lg*8];
      bf16x8 bm = *(const bf16x8*)&lds[NSPLIT+1][r][lg*8];
      bf16x8 bl;
      if (NSPLIT == 3) bl = *(const bf16x8*)&lds[NSPLIT+2][r][lg*8];
      #pragma unroll
      for (int i = 0; i < 4; i++){
        f32x4 c = acc[i][j];
        c = __builtin_amdgcn_mfma_f32_16x16x32_bf16(afh[i], bh, c, 0, 0, 0);
        c = __builtin_amdgcn_mfma_f32_16x16x32_bf16(afh[i], bm, c, 0, 0, 0);
        c = __builtin_amdgcn_mfma_f32_16x16x32_bf16(afm[i], bh, c, 0, 0, 0);
        if (NSPLIT == 3){
          c = __builtin_amdgcn_mfma_f32_16x16x32_bf16(afh[i], bl, c, 0, 0, 0);
          c = __builtin_amdgcn_mfma_f32_16x16x32_bf16(afl[i], bh, c, 0, 0, 0);
          c = __builtin_amdgcn_mfma_f32_16x16x32_bf16(afm[i], bm, c, 0, 0, 0);
        }
        acc[i][j] = c;
      }
    }
    __syncthreads();
  }

  // epilogue: C/D layout col = lane&15, row = (lane>>4)*4 + reg  [m89/m91]
  #pragma unroll
  for (int i = 0; i < 4; i++){
    #pragma unroll
    for (int j = 0; j < 4; j++){
      #pragma unroll
      for (int r = 0; r < 4; r++){
        int row = m0 + wr + i*16 + lg*4 + r;
        int col = n0 + wc + j*16 + lrow;
        float val = acc[i][j][r];
        if (MODE == 0){
          C[((size_t)b << 20) + ((size_t)row << 10) + col] = val;
        } else {
          int ch = col >> 8;
          int py = (col >> 4) & 15;
          int px = col & 15;
          int yy = ((row >> 5) << 4) + py;
          int xx = ((row & 31) << 4) + px;
          out[((size_t)(b*12 + ch) * 512 + yy) * 512 + xx] = val;
        }
      }
    }
  }
}

// ---------- kernel 5: row softmax + argmax; P written as split bf16 in place ----------
// row layout after this kernel: [1024 x bf16 Ph][1024 x bf16 Pm] per 4KB sim row
__global__ __launch_bounds__(256) void k_softmax(float* __restrict__ sim,
                                                 int* __restrict__ hard){
  const int row = blockIdx.x;               // b*1024 + n
  float* p = sim + (size_t)row * 1024;
  const int t = threadIdx.x;
  float4 v = ((const float4*)p)[t];

  float mx = v.x; int mi = 0;
  if (v.y > mx){ mx = v.y; mi = 1; }
  if (v.z > mx){ mx = v.z; mi = 2; }
  if (v.w > mx){ mx = v.w; mi = 3; }
  mi += t * 4;
  #pragma unroll
  for (int off = 32; off > 0; off >>= 1){
    float omx = __shfl_down(mx, off);
    int   omi = __shfl_down(mi, off);
    if (omx > mx || (omx == mx && omi < mi)){ mx = omx; mi = omi; }
  }
  __shared__ float wmx[4];
  __shared__ int   wmi[4];
  if ((t & 63) == 0){ wmx[t >> 6] = mx; wmi[t >> 6] = mi; }
  __syncthreads();
  mx = wmx[0]; mi = wmi[0];
  #pragma unroll
  for (int w = 1; w < 4; w++){
    if (wmx[w] > mx || (wmx[w] == mx && wmi[w] < mi)){ mx = wmx[w]; mi = wmi[w]; }
  }

  float e0 = expf(v.x - mx), e1 = expf(v.y - mx);
  float e2 = expf(v.z - mx), e3 = expf(v.w - mx);
  float s = e0 + e1 + e2 + e3;
  #pragma unroll
  for (int off = 32; off > 0; off >>= 1) s += __shfl_down(s, off);
  __shared__ float ws[4];
  if ((t & 63) == 0) ws[t >> 6] = s;
  __syncthreads();
  s = ws[0] + ws[1] + ws[2] + ws[3];
  float inv = 1.f / s;
  float o[4] = {e0*inv, e1*inv, e2*inv, e3*inv};

  __syncthreads();   // all reads of this row complete before overwrite
  short h[4], m[4];
  #pragma unroll
  for (int e = 0; e < 4; e++) split2v(o[e], h[e], m[e]);
  short* rowp = (short*)p;
  *(bf16x4*)(rowp + t*4)        = (bf16x4){h[0],h[1],h[2],h[3]};
  *(bf16x4*)(rowp + 1024 + t*4) = (bf16x4){m[0],m[1],m[2],m[3]};
  if (t == 0) hard[row] = mi;
}

// ---------- kernel 7: hard-assignment gather, recomputing [ms,grad,diff] ----------
__global__ __launch_bounds__(256) void k_gather(const float* __restrict__ ms,
                                                const float* __restrict__ kw,
                                                const int* __restrict__ hard,
                                                float* __restrict__ out){
  int x = blockIdx.x * 256 + threadIdx.x;
  int y = blockIdx.y;
  int z = blockIdx.z;             // b*3 + c
  int b = z / 3, c = z % 3;
  int n = ((y >> 4) << 5) + (x >> 4);
  int idx = hard[(b << 10) + n];
  int sy = ((idx >> 5) << 4) + (y & 15);
  int sx = ((idx & 31) << 4) + (x & 15);
  const float* base = ms + (size_t)(b*3 + c) * 262144;
  float v[3][3];
  #pragma unroll
  for (int dy = 0; dy < 3; dy++){
    int yy = sy + dy - 1;
    #pragma unroll
    for (int dx = 0; dx < 3; dx++){
      int xx = sx + dx - 1;
      v[dy][dx] = (yy >= 0 && yy < 512 && xx >= 0 && xx < 512)
                  ? base[(size_t)yy * 512 + xx] : 0.f;
    }
  }
  float conv = 0.f;
  #pragma unroll
  for (int dy = 0; dy < 3; dy++)
    #pragma unroll
    for (int dx = 0; dx < 3; dx++)
      conv = fmaf(v[dy][dx], kw[c*9 + dy*3 + dx], conv);
  float gv = v[2][1] - v[0][1];
  float gh = v[1][2] - v[1][0];
  float g  = sqrtf(gv*gv + gh*gh + 1e-6f);
  float ctr  = v[1][1];
  float diff = ctr - conv;
  size_t o = ((size_t)(b*12 + 3 + c) * 512 + y) * 512 + x;
  out[o]            = ctr;   // ch 3..5
  out[o + 3*262144] = g;     // ch 6..8
  out[o + 6*262144] = diff;  // ch 9..11
}

// ---------- launcher ----------
extern "C" void kernel_launch(void* const* d_in, const int* in_sizes, int n_in,
                              void* d_out, int out_size, void* d_ws, size_t ws_size,
                              hipStream_t stream){
  const float* hs = (const float*)d_in[0];   // (4,128,512,512)
  const float* ms = (const float*)d_in[1];   // (4,3,512,512)
  const float* sm = (const float*)d_in[2];   // (128,3)
  const float* kw = (const float*)d_in[3];   // (3,1,3,3)
  float* out = (float*)d_out;                // (4,12,512,512)

  const size_t CE = 3145728;                 // elements per bf16 comp (4*1024*768)
  short* w = (short*)d_ws;
  short* hph = w;            short* hpm = hph + CE;  short* hpl = hpm + CE;
  short* mph = hpl + CE;     short* mpm = mph + CE;  short* mpl = mpm + CE;
  short* mpTh = mpl + CE;    short* mpTm = mpTh + CE;
  float* sim = (float*)(mpTm + CE);          // 16,777,216 B (4,1024,1024) fp32
  int*   hard = (int*)(sim + 4194304);       // 16,384 B     -> total 67,125,248 B

  k_spectral <<<dim3(256, 4),    256, 0, stream>>>(hs, sm, hph, hpm, hpl);
  k_msprep   <<<dim3(1024, 4),   256, 0, stream>>>(ms, kw, mph, mpm, mpl);
  k_transpose<<<dim3(16, 12, 4), 256, 0, stream>>>(mph, mpTh);
  k_transpose<<<dim3(16, 12, 4), 256, 0, stream>>>(mpm, mpTm);
  // sim = hp . mp^T  (A=hp rows n, B=mp rows m, K=768)
  k_gemm<0, 768, 768, 768, 3><<<dim3(8, 8, 4), 256, 0, stream>>>(
      hph, hpm, hpl, mph, mpm, mpl, sim, nullptr);
  k_softmax  <<<dim3(4096),      256, 0, stream>>>(sim, hard);
  // soft = P . mp  (A=P rows n stride 2048, B=mpT rows d, K=1024)
  k_gemm<1, 1024, 2048, 1024, 2><<<dim3(6, 8, 4), 256, 0, stream>>>(
      (const short*)sim, (const short*)sim + 1024, nullptr,
      mpTh, mpTm, nullptr, nullptr, out);
  k_gather   <<<dim3(2, 512, 12), 256, 0, stream>>>(ms, kw, hard, out);
}